// Round 4
// baseline (275.322 us; speedup 1.0000x reference)
//
#include <hip/hip_runtime.h>
#include <hip/hip_cooperative_groups.h>
#include <math.h>

namespace cg = cooperative_groups;

#define N2   256
#define DIM  768
#define EPSF 1e-8f

// ws layout (float offsets). Every word is written before read on every call
// -> no zero-init needed despite 0xAA poison. Total ~530 KB.
// NOTE (measured R6): same-address device atomicAdd costs ~10us/1000 in tail
// serialization -> slots + 1-block finalize kernel is the faster pattern.
// NOTE (measured R4): __threadfence() in hot blocks = per-block L2 writeback/
// invalidate storm (60us angle). Kernel boundaries are the free coherence pt.
// NOTE (R9): GEMM uses bf16 MFMA (fp32->bf16 RNE at staging); symmetric
// dot-product uses make tile-transpose conventions cancel.
// NOTE (R10, measured R13): split-K-8 -> full-K Gram. Only -3 us: the 123 MB
// partial re-read was LLC-resident (~3 us), not the bottleneck.
// NOTE (R13 decomposition): dur_us tracks fill_dur + ~37 us across runs ->
// timed window includes the harness 256 MiB poison fill (~40 us). Residual
// ~37 us = ~10-12 us kernel work + ~25 us for 3 dependent launches (dispatch
// + drain each). This round: single cooperative kernel, 2 grid.sync()
// barriers replace 2 kernel boundaries (grid.sync does the L2 coherence).
#define OFF_G     0u          // [2][65536] reduced Gram (s, t)   512 KB
#define OFF_DIAG  131072u     // [2][256]   diagonals
#define OFF_TSUM  131584u     // [2][64]    per-tile sums
#define OFF_SLOT  131712u     // [896] per-block result slots
#define SL_ANG  0     // [512]
#define SL_DIST 512   // [256]
#define SL_CON  768   // [128]

typedef __attribute__((ext_vector_type(8))) short short8;   // 8 bf16 = 4 VGPRs
typedef __attribute__((ext_vector_type(4))) float f32x4;

__device__ inline float wave_reduce_sum(float v) {
    #pragma unroll
    for (int o = 32; o > 0; o >>= 1) v += __shfl_down(v, o, 64);
    return v;
}
__device__ inline float wave_reduce_max(float v) {
    #pragma unroll
    for (int o = 32; o > 0; o >>= 1) v = fmaxf(v, __shfl_down(v, o, 64));
    return v;
}
__device__ inline float block_reduce_sum(float v, volatile float* red) {
    float w = wave_reduce_sum(v);
    __syncthreads();
    if ((threadIdx.x & 63) == 0) red[threadIdx.x >> 6] = w;
    __syncthreads();
    return red[0] + red[1] + red[2] + red[3];
}
__device__ inline const float* rowptr(const float* q, const float* p, int r) {
    return (r < 128) ? (r * DIM + q) : ((r - 128) * DIM + p);
}
__device__ inline unsigned f2bf(float x) {      // fp32 -> bf16 (RNE)
    union { float f; unsigned u; } v; v.f = x;
    return (v.u + 0x7fffu + ((v.u >> 16) & 1u)) >> 16;
}

// ---------------------------------------------------------------------------
// Fused kernel, cooperative launch. 896 blocks x 256 threads.
// Phase A (blocks 0..127): full-K Gram GEMM, 32x32 tile/block, 8 pipelined
//   k-chunks of 96, bf16 MFMA. Writes Gram + diag + tile-sums.
// grid.sync()
// Phase B: blocks 0..511 angle, 512..767 dist rows, 768..895 contrastive.
// grid.sync()
// Phase C: block 0 finalizes into out.
// LDS: union(gemm 13.3 KB, angle 36.9 KB) -> 4 blocks/CU, capacity 1024 >= 896.
// ---------------------------------------------------------------------------
__global__ __launch_bounds__(256, 4) void fused_kernel(
        const float* __restrict__ sq, const float* __restrict__ sp,
        const float* __restrict__ tq, const float* __restrict__ tp,
        float* __restrict__ ws, float* __restrict__ out) {
    __shared__ union {
        struct { unsigned short A[32][104]; unsigned short B[32][104]; } g;
        struct { float GJ[16][68], TJ[16][68], IJ[16][68], ITJ[16][68];
                 float GI[32][68], TI[32][68];
                 float dgS[256], dgT[256]; } a;
    } sm;
    __shared__ float red1[4], red2[4], redS[1];
    const int b = blockIdx.x, t = threadIdx.x;
    cg::grid_group grid = cg::this_grid();

    // ======================= Phase A: Gram GEMM =======================
    if (b < 128) {
        const int mat = b & 1, tile = b >> 1;
        const int m0 = (tile >> 3) * 32, n0 = (tile & 7) * 32;
        const float* q = mat ? tq : sq;
        const float* p = mat ? tp : sp;

        // staging: 8 threads/row, each owns 12 floats (3 float4) per array
        const int srow = t >> 3, skq = (t & 7) * 12;
        const float* arow = rowptr(q, p, m0 + srow) + skq;
        const float* brow = rowptr(q, p, n0 + srow) + skq;

        float4 pa[3], pb[3];
        #pragma unroll
        for (int m = 0; m < 3; ++m) {
            pa[m] = *(const float4*)&arow[4 * m];
            pb[m] = *(const float4*)&brow[4 * m];
        }

        const int wave = t >> 6, lane = t & 63;
        const int wm = (wave >> 1) * 16, wn = (wave & 1) * 16;
        const int fr = lane & 15;          // fragment row/col
        const int fk = (lane >> 4) * 8;    // fragment k base
        f32x4 acc = {0.f, 0.f, 0.f, 0.f};

        for (int c = 0; c < 8; ++c) {
            // convert prefetched regs -> LDS
            #pragma unroll
            for (int m = 0; m < 3; ++m) {
                uint2 ap, bp;
                ap.x = f2bf(pa[m].x) | (f2bf(pa[m].y) << 16);
                ap.y = f2bf(pa[m].z) | (f2bf(pa[m].w) << 16);
                bp.x = f2bf(pb[m].x) | (f2bf(pb[m].y) << 16);
                bp.y = f2bf(pb[m].z) | (f2bf(pb[m].w) << 16);
                *(uint2*)&sm.g.A[srow][skq + 4 * m] = ap;
                *(uint2*)&sm.g.B[srow][skq + 4 * m] = bp;
            }
            __syncthreads();
            if (c < 7) {      // prefetch next chunk; waitcnt lands at next convert
                const int kb = (c + 1) * 96;
                #pragma unroll
                for (int m = 0; m < 3; ++m) {
                    pa[m] = *(const float4*)&arow[kb + 4 * m];
                    pb[m] = *(const float4*)&brow[kb + 4 * m];
                }
            }
            #pragma unroll
            for (int kc = 0; kc < 96; kc += 32) {
                const short8 a0 = *(const short8*)&sm.g.A[wm + fr][kc + fk];
                const short8 b0 = *(const short8*)&sm.g.B[wn + fr][kc + fk];
                acc = __builtin_amdgcn_mfma_f32_16x16x32_bf16(a0, b0, acc, 0, 0, 0);
            }
            __syncthreads();
        }

        // epilogue: C/D layout row=(lane>>4)*4+reg, col=lane&15
        float* G = ws + OFF_G + (unsigned)mat * 65536u;
        const int crow0 = (lane >> 4) * 4;
        const int ccol = lane & 15;
        float ts = 0.f;
        #pragma unroll
        for (int reg = 0; reg < 4; ++reg) {
            const int row = m0 + wm + crow0 + reg;
            const int col = n0 + wn + ccol;
            G[row * 256 + col] = acc[reg];
            ts += acc[reg];
        }
        if (m0 == n0 && wm == wn && (lane >> 4) == (ccol >> 2)) {
            // diagonal lanes: reg = ccol&3 hits row==col within diagonal quadrant
            ws[OFF_DIAG + (unsigned)(mat * 256 + m0 + wm + ccol)] = acc[ccol & 3];
        }
        const float tsum = block_reduce_sum(ts, red1);
        if (t == 0) ws[OFF_TSUM + (unsigned)(mat * 64 + tile)] = tsum;
    }

    grid.sync();   // Gram/diag/tsum visible device-wide

    // ======================= Phase B =======================
    const float* Pg = ws + OFF_G;      // [2][65536]
    const float* Dg = ws + OFF_DIAG;   // [2][256]

    if (b < 512) {
        // ---------------- angle ----------------
        const int k0 = (b & 3) * 64;
        const int j0 = ((b >> 2) & 15) * 16;
        const int i0 = (b >> 6) * 32;
        const int jj = t & 15, ii = t >> 4;
        const int i1 = i0 + ii, i2 = i1 + 16, j = j0 + jj;

        __syncthreads();   // phase-A LDS (union) fully retired before reuse

        // diag (thread t owns index t)
        sm.a.dgS[t] = Dg[t];
        sm.a.dgT[t] = Dg[256 + t];

        // J-side G rows -> registers (1 float4 slot/thread)
        const int r = t >> 4, c4 = (t & 15) * 4;
        const unsigned baseJ = (unsigned)((j0 + r) * 256 + k0 + c4);
        const float4 gjs = *(const float4*)&Pg[baseJ];
        const float4 gjt = *(const float4*)&Pg[65536u + baseJ];

        // I-side G rows -> LDS (2 float4 slots/thread)
        #pragma unroll
        for (int s2 = 0; s2 < 2; ++s2) {
            const int slot = t + 256 * s2;
            const int ri = slot >> 4, ci = (slot & 15) * 4;
            const unsigned base = (unsigned)((i0 + ri) * 256 + k0 + ci);
            *(float4*)&sm.a.GI[ri][ci] = *(const float4*)&Pg[base];
            *(float4*)&sm.a.TI[ri][ci] = *(const float4*)&Pg[65536u + base];
        }
        // per-thread G[i1,j], G[i2,j] (both mats)
        const float g1s = Pg[(unsigned)(i1 * 256 + j)];
        const float g1t = Pg[65536u + (unsigned)(i1 * 256 + j)];
        const float g2s = Pg[(unsigned)(i2 * 256 + j)];
        const float g2t = Pg[65536u + (unsigned)(i2 * 256 + j)];
        __syncthreads();   // dgS/dgT ready

        // write J arrays + on-the-fly INV
        {
            const float djs = sm.a.dgS[j0 + r], djt = sm.a.dgT[j0 + r];
            float4 ivs, ivt;
            const float* dS = &sm.a.dgS[k0 + c4];
            const float* dT = &sm.a.dgT[k0 + c4];
            ivs.x = 1.f / (sqrtf(fmaxf(djs + dS[0] - 2.f * gjs.x, 0.f)) + EPSF);
            ivs.y = 1.f / (sqrtf(fmaxf(djs + dS[1] - 2.f * gjs.y, 0.f)) + EPSF);
            ivs.z = 1.f / (sqrtf(fmaxf(djs + dS[2] - 2.f * gjs.z, 0.f)) + EPSF);
            ivs.w = 1.f / (sqrtf(fmaxf(djs + dS[3] - 2.f * gjs.w, 0.f)) + EPSF);
            ivt.x = 1.f / (sqrtf(fmaxf(djt + dT[0] - 2.f * gjt.x, 0.f)) + EPSF);
            ivt.y = 1.f / (sqrtf(fmaxf(djt + dT[1] - 2.f * gjt.y, 0.f)) + EPSF);
            ivt.z = 1.f / (sqrtf(fmaxf(djt + dT[2] - 2.f * gjt.z, 0.f)) + EPSF);
            ivt.w = 1.f / (sqrtf(fmaxf(djt + dT[3] - 2.f * gjt.w, 0.f)) + EPSF);
            *(float4*)&sm.a.GJ[r][c4] = gjs;
            *(float4*)&sm.a.TJ[r][c4] = gjt;
            *(float4*)&sm.a.IJ[r][c4] = ivs;
            *(float4*)&sm.a.ITJ[r][c4] = ivt;
        }
        // per-thread constants
        const float Gjj = sm.a.dgS[j], Tjj = sm.a.dgT[j];
        const float wis1 = 1.f / (sqrtf(fmaxf(sm.a.dgS[i1] + Gjj - 2.f * g1s, 0.f)) + EPSF);
        const float wit1 = 1.f / (sqrtf(fmaxf(sm.a.dgT[i1] + Tjj - 2.f * g1t, 0.f)) + EPSF);
        const float wis2 = 1.f / (sqrtf(fmaxf(sm.a.dgS[i2] + Gjj - 2.f * g2s, 0.f)) + EPSF);
        const float wit2 = 1.f / (sqrtf(fmaxf(sm.a.dgT[i2] + Tjj - 2.f * g2t, 0.f)) + EPSF);
        const float as1 = (Gjj - g1s) * wis1;
        const float at1 = (Tjj - g1t) * wit1;
        const float as2 = (Gjj - g2s) * wis2;
        const float at2 = (Tjj - g2t) * wit2;
        __syncthreads();   // all arrays ready

        float sum1 = 0.f, sum2 = 0.f;
        for (int c = 0; c < 64; c += 4) {
            const float4 gJ  = *(const float4*)&sm.a.GJ[jj][c];
            const float4 iJ  = *(const float4*)&sm.a.IJ[jj][c];
            const float4 tJ  = *(const float4*)&sm.a.TJ[jj][c];
            const float4 itJ = *(const float4*)&sm.a.ITJ[jj][c];
            const float4 a1 = *(const float4*)&sm.a.GI[ii][c];
            const float4 b1 = *(const float4*)&sm.a.TI[ii][c];
            const float4 a2 = *(const float4*)&sm.a.GI[ii + 16][c];
            const float4 b2 = *(const float4*)&sm.a.TI[ii + 16][c];
            const float gJr[4]  = {gJ.x, gJ.y, gJ.z, gJ.w};
            const float iJr[4]  = {iJ.x, iJ.y, iJ.z, iJ.w};
            const float tJr[4]  = {tJ.x, tJ.y, tJ.z, tJ.w};
            const float itJr[4] = {itJ.x, itJ.y, itJ.z, itJ.w};
            const float a1r[4] = {a1.x, a1.y, a1.z, a1.w};
            const float b1r[4] = {b1.x, b1.y, b1.z, b1.w};
            const float a2r[4] = {a2.x, a2.y, a2.z, a2.w};
            const float b2r[4] = {b2.x, b2.y, b2.z, b2.w};
            #pragma unroll
            for (int e = 0; e < 4; ++e) {
                const float ps1 = fmaf(wis1, a1r[e] - gJr[e], as1) * iJr[e];
                const float pt1 = fmaf(wit1, b1r[e] - tJr[e], at1) * itJr[e];
                const float d1 = ps1 - pt1;
                const float ad1 = fabsf(d1);
                const float m1 = fminf(ad1, 1.f);
                sum1 = fmaf(m1, fmaf(-0.5f, m1, ad1), sum1);

                const float ps2 = fmaf(wis2, a2r[e] - gJr[e], as2) * iJr[e];
                const float pt2 = fmaf(wit2, b2r[e] - tJr[e], at2) * itJr[e];
                const float d2 = ps2 - pt2;
                const float ad2 = fabsf(d2);
                const float m2 = fminf(ad2, 1.f);
                sum2 = fmaf(m2, fmaf(-0.5f, m2, ad2), sum2);
            }
        }
        const float v = block_reduce_sum(sum1 + sum2, red1);
        if (t == 0) ws[OFF_SLOT + SL_ANG + b] = v;
    } else if (b < 768) {
        // ---------------- distance row ----------------
        const int i = b - 512, j = t;
        const float gs  = Pg[(unsigned)(i * 256 + j)];
        const float gt  = Pg[65536u + (unsigned)(i * 256 + j)];
        const float djs = Dg[j], djt = Dg[256 + j];
        const float dis = Dg[i], dit = Dg[256 + i];
        const float ds = fmaxf(dis + djs - 2.f * gs, 0.f);
        const float dt = fmaxf(dit + djt - 2.f * gt, 0.f);

        // analytic masked pair-sums: sum_{i<j} d = N*tr - sum_all(G)
        const float tr_s = block_reduce_sum(djs, red1);
        const float tr_t = block_reduce_sum(djt, red1);
        const float tv = (t < 128) ? ws[OFF_TSUM + t] : 0.f;  // [2][64] linear
        const float sum_gs = block_reduce_sum((t < 64) ? tv : 0.f, red1);
        const float sum_gt = block_reduce_sum((t >= 64) ? tv : 0.f, red1);
        const float rs = 1.f / ((256.f * tr_s - sum_gs) / 32640.f + EPSF);
        const float rt = 1.f / ((256.f * tr_t - sum_gt) / 32640.f + EPSF);

        const float dd = ds * rs - dt * rt;
        const float a = fabsf(dd);
        const float m = fminf(a, 1.f);
        const float hv = block_reduce_sum((j > i) ? m * fmaf(-0.5f, m, a) : 0.f, red1);
        if (t == 0) ws[OFF_SLOT + SL_DIST + i] = hv;
    } else {
        // ---------------- contrastive row ----------------
        const int rrow = b - 768, j = t;
        const float gs = (j >= 128) ? Pg[(unsigned)(rrow * 256 + j)] : 0.f;
        const float s = (j >= 128) ? 20.f * gs : -INFINITY;
        if (j == 128 + rrow) redS[0] = s;     // diag score
        float mx0 = wave_reduce_max(s);
        __syncthreads();
        if ((t & 63) == 0) red2[t >> 6] = mx0;
        __syncthreads();
        const float mx = fmaxf(fmaxf(red2[0], red2[1]), fmaxf(red2[2], red2[3]));
        const float e = block_reduce_sum((j >= 128) ? expf(s - mx) : 0.f, red1);
        if (t == 0) ws[OFF_SLOT + SL_CON + rrow] = mx + logf(e) - redS[0];
    }

    grid.sync();   // all slots visible device-wide

    // ======================= Phase C: finalize =======================
    if (b == 0) {
        const float* S = ws + OFF_SLOT;
        const float a_ = block_reduce_sum(S[SL_ANG + t] + S[SL_ANG + 256 + t], red1);
        const float d_ = block_reduce_sum(S[SL_DIST + t], red1);
        const float c_ = block_reduce_sum((t < 128) ? S[SL_CON + t] : 0.f, red1);
        if (t == 0) {
            const float contrastive = c_ / 128.f;
            const float dist = d_ / 32640.f;
            const float ang = a_ / 16581120.f;   // 256*255*254
            const float kd = 0.5f * (dist + ang);
            out[0] = contrastive + kd;
            out[1] = contrastive;
            out[2] = kd;
        }
    }
}

extern "C" void kernel_launch(void* const* d_in, const int* in_sizes, int n_in,
                              void* d_out, int out_size, void* d_ws, size_t ws_size,
                              hipStream_t stream) {
    (void)in_sizes; (void)n_in; (void)out_size; (void)ws_size;
    const float* sq = (const float*)d_in[0];
    const float* sp = (const float*)d_in[1];
    const float* tq = (const float*)d_in[2];
    const float* tp = (const float*)d_in[3];
    float* ws  = (float*)d_ws;
    float* out = (float*)d_out;

    void* args[] = { (void*)&sq, (void*)&sp, (void*)&tq, (void*)&tp,
                     (void*)&ws, (void*)&out };
    hipLaunchCooperativeKernel(fused_kernel, dim3(896), dim3(256),
                               args, 0u, stream);
}

// Round 5
// 108.298 us; speedup vs baseline: 2.5423x; 2.5423x over previous
//
#include <hip/hip_runtime.h>
#include <math.h>

#define N2   256
#define DIM  768
#define EPSF 1e-8f
#define MAGIC 0x5A17F00Du

// ws layout (float offsets). Every word is written before read on every call
// (flags rely on the per-call 0xAA poison != MAGIC). Total ~534 KB.
// NOTE (measured R6): same-address device atomicAdd ~10us/1000 tail -> use
// per-block flags (distinct addresses), not a shared counter.
// NOTE (measured R4/R14): __threadfence()/grid.sync() = per-block buffer_wbl2
// + buffer_inv; 896 blocks x 2 syncs = 204us kernel (VALUBusy 3%). Device-
// scope coherence must be flag+sc1 handshakes, never wholesale L2 flushes.
// NOTE (R9): GEMM uses bf16 MFMA (fp32->bf16 RNE at staging); symmetric
// dot-product uses make tile-transpose conventions cancel.
// NOTE (R10, measured R13): full-K Gram (no split-K partials). 123MB partial
// re-read was LLC-resident (~3us) -> only -3us; traffic wasn't the bottleneck.
// NOTE (R13 decomposition): dur_us = harness 256MiB poison fill (~40us) +
// ~8us kernel work + ~30us of dispatch gaps (3 dependent nodes). This round:
// single cooperative kernel, flag barriers (no grid.sync).
#define OFF_G     0u          // [2][65536] reduced Gram (s, t)   512 KB
#define OFF_DIAG  131072u     // [2][256]   diagonals
#define OFF_TSUM  131584u     // [2][64]    per-tile sums
#define OFF_SLOT  131712u     // [896] per-block result slots
#define OFF_FLAG1 132608u     // [128] gemm-done flags
#define OFF_FLAG2 132736u     // [896] phaseB-done flags
#define SL_ANG  0     // [512]
#define SL_DIST 512   // [256]
#define SL_CON  768   // [128]

typedef __attribute__((ext_vector_type(8))) short short8;   // 8 bf16 = 4 VGPRs
typedef __attribute__((ext_vector_type(4))) float f32x4;

__device__ inline float wave_reduce_sum(float v) {
    #pragma unroll
    for (int o = 32; o > 0; o >>= 1) v += __shfl_down(v, o, 64);
    return v;
}
__device__ inline float wave_reduce_max(float v) {
    #pragma unroll
    for (int o = 32; o > 0; o >>= 1) v = fmaxf(v, __shfl_down(v, o, 64));
    return v;
}
__device__ inline float block_reduce_sum(float v, volatile float* red) {
    float w = wave_reduce_sum(v);
    __syncthreads();
    if ((threadIdx.x & 63) == 0) red[threadIdx.x >> 6] = w;
    __syncthreads();
    return red[0] + red[1] + red[2] + red[3];
}
__device__ inline const float* rowptr(const float* q, const float* p, int r) {
    return (r < 128) ? (r * DIM + q) : ((r - 128) * DIM + p);
}
__device__ inline unsigned f2bf(float x) {      // fp32 -> bf16 (RNE)
    union { float f; unsigned u; } v; v.f = x;
    return (v.u + 0x7fffu + ((v.u >> 16) & 1u)) >> 16;
}
// agent-scope (sc1) accessors: write-through / L2-bypass, NO cache flushes.
__device__ inline void st_agent_f(float* p, float v) {
    __hip_atomic_store(p, v, __ATOMIC_RELAXED, __HIP_MEMORY_SCOPE_AGENT);
}
__device__ inline void st_agent_u(unsigned* p, unsigned v) {
    __hip_atomic_store(p, v, __ATOMIC_RELAXED, __HIP_MEMORY_SCOPE_AGENT);
}
__device__ inline unsigned ld_agent_u(const unsigned* p) {
    return __hip_atomic_load(p, __ATOMIC_RELAXED, __HIP_MEMORY_SCOPE_AGENT);
}

// ---------------------------------------------------------------------------
// Fused kernel, cooperative launch (residency guarantee only; no grid.sync).
// 896 blocks x 256 threads.
// Phase A (blocks 0..127): full-K Gram GEMM -> sc1 stores -> flag1[b].
// All blocks spin flag1[0..127] (sc1 loads), then phase B:
//   blocks 0..511 angle, 512..767 dist rows, 768..895 contrastive.
//   Slot sc1 store -> vmcnt(0) -> flag2[b].
// Block 0 spins flag2[0..895], then finalizes into out.
// LDS union 36.9 KB -> 4 blocks/CU -> 1024 co-resident >= 896.
// ---------------------------------------------------------------------------
__global__ __launch_bounds__(256, 4) void fused_kernel(
        const float* __restrict__ sq, const float* __restrict__ sp,
        const float* __restrict__ tq, const float* __restrict__ tp,
        float* __restrict__ ws, float* __restrict__ out) {
    __shared__ union {
        struct { unsigned short A[32][104]; unsigned short B[32][104]; } g;
        struct { float GJ[16][68], TJ[16][68], IJ[16][68], ITJ[16][68];
                 float GI[32][68], TI[32][68];
                 float dgS[256], dgT[256]; } a;
    } sm;
    __shared__ float red1[4], red2[4], redS[1];
    const int b = blockIdx.x, t = threadIdx.x;

    // ======================= Phase A: Gram GEMM =======================
    if (b < 128) {
        const int mat = b & 1, tile = b >> 1;
        const int m0 = (tile >> 3) * 32, n0 = (tile & 7) * 32;
        const float* q = mat ? tq : sq;
        const float* p = mat ? tp : sp;

        // staging: 8 threads/row, each owns 12 floats (3 float4) per array
        const int srow = t >> 3, skq = (t & 7) * 12;
        const float* arow = rowptr(q, p, m0 + srow) + skq;
        const float* brow = rowptr(q, p, n0 + srow) + skq;

        float4 pa[3], pb[3];
        #pragma unroll
        for (int m = 0; m < 3; ++m) {
            pa[m] = *(const float4*)&arow[4 * m];
            pb[m] = *(const float4*)&brow[4 * m];
        }

        const int wave = t >> 6, lane = t & 63;
        const int wm = (wave >> 1) * 16, wn = (wave & 1) * 16;
        const int fr = lane & 15;          // fragment row/col
        const int fk = (lane >> 4) * 8;    // fragment k base
        f32x4 acc = {0.f, 0.f, 0.f, 0.f};

        for (int c = 0; c < 8; ++c) {
            // convert prefetched regs -> LDS
            #pragma unroll
            for (int m = 0; m < 3; ++m) {
                uint2 ap, bp;
                ap.x = f2bf(pa[m].x) | (f2bf(pa[m].y) << 16);
                ap.y = f2bf(pa[m].z) | (f2bf(pa[m].w) << 16);
                bp.x = f2bf(pb[m].x) | (f2bf(pb[m].y) << 16);
                bp.y = f2bf(pb[m].z) | (f2bf(pb[m].w) << 16);
                *(uint2*)&sm.g.A[srow][skq + 4 * m] = ap;
                *(uint2*)&sm.g.B[srow][skq + 4 * m] = bp;
            }
            __syncthreads();
            if (c < 7) {      // prefetch next chunk
                const int kb = (c + 1) * 96;
                #pragma unroll
                for (int m = 0; m < 3; ++m) {
                    pa[m] = *(const float4*)&arow[kb + 4 * m];
                    pb[m] = *(const float4*)&brow[kb + 4 * m];
                }
            }
            #pragma unroll
            for (int kc = 0; kc < 96; kc += 32) {
                const short8 a0 = *(const short8*)&sm.g.A[wm + fr][kc + fk];
                const short8 b0 = *(const short8*)&sm.g.B[wn + fr][kc + fk];
                acc = __builtin_amdgcn_mfma_f32_16x16x32_bf16(a0, b0, acc, 0, 0, 0);
            }
            __syncthreads();
        }

        // epilogue: C/D layout row=(lane>>4)*4+reg, col=lane&15
        // sc1 stores -> data lands at LLC, visible to all XCDs post-flag.
        float* G = ws + OFF_G + (unsigned)mat * 65536u;
        const int crow0 = (lane >> 4) * 4;
        const int ccol = lane & 15;
        float ts = 0.f;
        #pragma unroll
        for (int reg = 0; reg < 4; ++reg) {
            const int row = m0 + wm + crow0 + reg;
            const int col = n0 + wn + ccol;
            st_agent_f(&G[row * 256 + col], acc[reg]);
            ts += acc[reg];
        }
        if (m0 == n0 && wm == wn && (lane >> 4) == (ccol >> 2)) {
            // diagonal lanes: reg = ccol&3 hits row==col within diag quadrant
            st_agent_f(&ws[OFF_DIAG + (unsigned)(mat * 256 + m0 + wm + ccol)],
                       acc[ccol & 3]);
        }
        const float tsum = block_reduce_sum(ts, red1);   // syncthreads drains all waves' stores
        if (t == 0) {
            st_agent_f(&ws[OFF_TSUM + (unsigned)(mat * 64 + tile)], tsum);
            asm volatile("s_waitcnt vmcnt(0)" ::: "memory");
            st_agent_u((unsigned*)(ws + OFF_FLAG1) + b, MAGIC);
        }
    }

    // ---- barrier 1: Gram ready. Flag spin (sc1 loads), zero cache flushes.
    if (t < 128) {
        while (ld_agent_u((const unsigned*)(ws + OFF_FLAG1) + t) != MAGIC)
            __builtin_amdgcn_s_sleep(4);
    }
    __builtin_amdgcn_sched_barrier(0);
    asm volatile("" ::: "memory");
    __syncthreads();   // also retires phase-A LDS (union) before reuse

    // ======================= Phase B =======================
    const float* Pg = ws + OFF_G;      // [2][65536]  (normal cached loads: no
    const float* Dg = ws + OFF_DIAG;   //  XCD L2 ever held stale lines here)

    if (b < 512) {
        // ---------------- angle ----------------
        const int k0 = (b & 3) * 64;
        const int j0 = ((b >> 2) & 15) * 16;
        const int i0 = (b >> 6) * 32;
        const int jj = t & 15, ii = t >> 4;
        const int i1 = i0 + ii, i2 = i1 + 16, j = j0 + jj;

        // diag (thread t owns index t)
        sm.a.dgS[t] = Dg[t];
        sm.a.dgT[t] = Dg[256 + t];

        // J-side G rows -> registers (1 float4 slot/thread)
        const int r = t >> 4, c4 = (t & 15) * 4;
        const unsigned baseJ = (unsigned)((j0 + r) * 256 + k0 + c4);
        const float4 gjs = *(const float4*)&Pg[baseJ];
        const float4 gjt = *(const float4*)&Pg[65536u + baseJ];

        // I-side G rows -> LDS (2 float4 slots/thread)
        #pragma unroll
        for (int s2 = 0; s2 < 2; ++s2) {
            const int slot = t + 256 * s2;
            const int ri = slot >> 4, ci = (slot & 15) * 4;
            const unsigned base = (unsigned)((i0 + ri) * 256 + k0 + ci);
            *(float4*)&sm.a.GI[ri][ci] = *(const float4*)&Pg[base];
            *(float4*)&sm.a.TI[ri][ci] = *(const float4*)&Pg[65536u + base];
        }
        // per-thread G[i1,j], G[i2,j] (both mats)
        const float g1s = Pg[(unsigned)(i1 * 256 + j)];
        const float g1t = Pg[65536u + (unsigned)(i1 * 256 + j)];
        const float g2s = Pg[(unsigned)(i2 * 256 + j)];
        const float g2t = Pg[65536u + (unsigned)(i2 * 256 + j)];
        __syncthreads();   // dgS/dgT ready

        // write J arrays + on-the-fly INV
        {
            const float djs = sm.a.dgS[j0 + r], djt = sm.a.dgT[j0 + r];
            float4 ivs, ivt;
            const float* dS = &sm.a.dgS[k0 + c4];
            const float* dT = &sm.a.dgT[k0 + c4];
            ivs.x = 1.f / (sqrtf(fmaxf(djs + dS[0] - 2.f * gjs.x, 0.f)) + EPSF);
            ivs.y = 1.f / (sqrtf(fmaxf(djs + dS[1] - 2.f * gjs.y, 0.f)) + EPSF);
            ivs.z = 1.f / (sqrtf(fmaxf(djs + dS[2] - 2.f * gjs.z, 0.f)) + EPSF);
            ivs.w = 1.f / (sqrtf(fmaxf(djs + dS[3] - 2.f * gjs.w, 0.f)) + EPSF);
            ivt.x = 1.f / (sqrtf(fmaxf(djt + dT[0] - 2.f * gjt.x, 0.f)) + EPSF);
            ivt.y = 1.f / (sqrtf(fmaxf(djt + dT[1] - 2.f * gjt.y, 0.f)) + EPSF);
            ivt.z = 1.f / (sqrtf(fmaxf(djt + dT[2] - 2.f * gjt.z, 0.f)) + EPSF);
            ivt.w = 1.f / (sqrtf(fmaxf(djt + dT[3] - 2.f * gjt.w, 0.f)) + EPSF);
            *(float4*)&sm.a.GJ[r][c4] = gjs;
            *(float4*)&sm.a.TJ[r][c4] = gjt;
            *(float4*)&sm.a.IJ[r][c4] = ivs;
            *(float4*)&sm.a.ITJ[r][c4] = ivt;
        }
        // per-thread constants
        const float Gjj = sm.a.dgS[j], Tjj = sm.a.dgT[j];
        const float wis1 = 1.f / (sqrtf(fmaxf(sm.a.dgS[i1] + Gjj - 2.f * g1s, 0.f)) + EPSF);
        const float wit1 = 1.f / (sqrtf(fmaxf(sm.a.dgT[i1] + Tjj - 2.f * g1t, 0.f)) + EPSF);
        const float wis2 = 1.f / (sqrtf(fmaxf(sm.a.dgS[i2] + Gjj - 2.f * g2s, 0.f)) + EPSF);
        const float wit2 = 1.f / (sqrtf(fmaxf(sm.a.dgT[i2] + Tjj - 2.f * g2t, 0.f)) + EPSF);
        const float as1 = (Gjj - g1s) * wis1;
        const float at1 = (Tjj - g1t) * wit1;
        const float as2 = (Gjj - g2s) * wis2;
        const float at2 = (Tjj - g2t) * wit2;
        __syncthreads();   // all arrays ready

        float sum1 = 0.f, sum2 = 0.f;
        for (int c = 0; c < 64; c += 4) {
            const float4 gJ  = *(const float4*)&sm.a.GJ[jj][c];
            const float4 iJ  = *(const float4*)&sm.a.IJ[jj][c];
            const float4 tJ  = *(const float4*)&sm.a.TJ[jj][c];
            const float4 itJ = *(const float4*)&sm.a.ITJ[jj][c];
            const float4 a1 = *(const float4*)&sm.a.GI[ii][c];
            const float4 b1 = *(const float4*)&sm.a.TI[ii][c];
            const float4 a2 = *(const float4*)&sm.a.GI[ii + 16][c];
            const float4 b2 = *(const float4*)&sm.a.TI[ii + 16][c];
            const float gJr[4]  = {gJ.x, gJ.y, gJ.z, gJ.w};
            const float iJr[4]  = {iJ.x, iJ.y, iJ.z, iJ.w};
            const float tJr[4]  = {tJ.x, tJ.y, tJ.z, tJ.w};
            const float itJr[4] = {itJ.x, itJ.y, itJ.z, itJ.w};
            const float a1r[4] = {a1.x, a1.y, a1.z, a1.w};
            const float b1r[4] = {b1.x, b1.y, b1.z, b1.w};
            const float a2r[4] = {a2.x, a2.y, a2.z, a2.w};
            const float b2r[4] = {b2.x, b2.y, b2.z, b2.w};
            #pragma unroll
            for (int e = 0; e < 4; ++e) {
                const float ps1 = fmaf(wis1, a1r[e] - gJr[e], as1) * iJr[e];
                const float pt1 = fmaf(wit1, b1r[e] - tJr[e], at1) * itJr[e];
                const float d1 = ps1 - pt1;
                const float ad1 = fabsf(d1);
                const float m1 = fminf(ad1, 1.f);
                sum1 = fmaf(m1, fmaf(-0.5f, m1, ad1), sum1);

                const float ps2 = fmaf(wis2, a2r[e] - gJr[e], as2) * iJr[e];
                const float pt2 = fmaf(wit2, b2r[e] - tJr[e], at2) * itJr[e];
                const float d2 = ps2 - pt2;
                const float ad2 = fabsf(d2);
                const float m2 = fminf(ad2, 1.f);
                sum2 = fmaf(m2, fmaf(-0.5f, m2, ad2), sum2);
            }
        }
        const float v = block_reduce_sum(sum1 + sum2, red1);
        if (t == 0) {
            st_agent_f(ws + OFF_SLOT + SL_ANG + b, v);
            asm volatile("s_waitcnt vmcnt(0)" ::: "memory");
            st_agent_u((unsigned*)(ws + OFF_FLAG2) + b, MAGIC);
        }
    } else if (b < 768) {
        // ---------------- distance row ----------------
        const int i = b - 512, j = t;
        const float gs  = Pg[(unsigned)(i * 256 + j)];
        const float gt  = Pg[65536u + (unsigned)(i * 256 + j)];
        const float djs = Dg[j], djt = Dg[256 + j];
        const float dis = Dg[i], dit = Dg[256 + i];
        const float ds = fmaxf(dis + djs - 2.f * gs, 0.f);
        const float dt = fmaxf(dit + djt - 2.f * gt, 0.f);

        // analytic masked pair-sums: sum_{i<j} d = N*tr - sum_all(G)
        const float tr_s = block_reduce_sum(djs, red1);
        const float tr_t = block_reduce_sum(djt, red1);
        const float tv = (t < 128) ? ws[OFF_TSUM + t] : 0.f;  // [2][64] linear
        const float sum_gs = block_reduce_sum((t < 64) ? tv : 0.f, red1);
        const float sum_gt = block_reduce_sum((t >= 64) ? tv : 0.f, red1);
        const float rs = 1.f / ((256.f * tr_s - sum_gs) / 32640.f + EPSF);
        const float rt = 1.f / ((256.f * tr_t - sum_gt) / 32640.f + EPSF);

        const float dd = ds * rs - dt * rt;
        const float a = fabsf(dd);
        const float m = fminf(a, 1.f);
        const float hv = block_reduce_sum((j > i) ? m * fmaf(-0.5f, m, a) : 0.f, red1);
        if (t == 0) {
            st_agent_f(ws + OFF_SLOT + SL_DIST + i, hv);
            asm volatile("s_waitcnt vmcnt(0)" ::: "memory");
            st_agent_u((unsigned*)(ws + OFF_FLAG2) + b, MAGIC);
        }
    } else {
        // ---------------- contrastive row ----------------
        const int rrow = b - 768, j = t;
        const float gs = (j >= 128) ? Pg[(unsigned)(rrow * 256 + j)] : 0.f;
        const float s = (j >= 128) ? 20.f * gs : -INFINITY;
        if (j == 128 + rrow) redS[0] = s;     // diag score
        float mx0 = wave_reduce_max(s);
        __syncthreads();
        if ((t & 63) == 0) red2[t >> 6] = mx0;
        __syncthreads();
        const float mx = fmaxf(fmaxf(red2[0], red2[1]), fmaxf(red2[2], red2[3]));
        const float e = block_reduce_sum((j >= 128) ? expf(s - mx) : 0.f, red1);
        if (t == 0) {
            st_agent_f(ws + OFF_SLOT + SL_CON + rrow, mx + logf(e) - redS[0]);
            asm volatile("s_waitcnt vmcnt(0)" ::: "memory");
            st_agent_u((unsigned*)(ws + OFF_FLAG2) + b, MAGIC);
        }
    }

    // ======================= Phase C: finalize (block 0) =======================
    if (b == 0) {
        for (int k = t; k < 896; k += 256) {
            while (ld_agent_u((const unsigned*)(ws + OFF_FLAG2) + k) != MAGIC)
                __builtin_amdgcn_s_sleep(4);
        }
        __builtin_amdgcn_sched_barrier(0);
        asm volatile("" ::: "memory");
        __syncthreads();

        const float* S = ws + OFF_SLOT;
        const float a_ = block_reduce_sum(S[SL_ANG + t] + S[SL_ANG + 256 + t], red1);
        const float d_ = block_reduce_sum(S[SL_DIST + t], red1);
        const float c_ = block_reduce_sum((t < 128) ? S[SL_CON + t] : 0.f, red1);
        if (t == 0) {
            const float contrastive = c_ / 128.f;
            const float dist = d_ / 32640.f;
            const float ang = a_ / 16581120.f;   // 256*255*254
            const float kd = 0.5f * (dist + ang);
            out[0] = contrastive + kd;
            out[1] = contrastive;
            out[2] = kd;
        }
    }
}

extern "C" void kernel_launch(void* const* d_in, const int* in_sizes, int n_in,
                              void* d_out, int out_size, void* d_ws, size_t ws_size,
                              hipStream_t stream) {
    (void)in_sizes; (void)n_in; (void)out_size; (void)ws_size;
    const float* sq = (const float*)d_in[0];
    const float* sp = (const float*)d_in[1];
    const float* tq = (const float*)d_in[2];
    const float* tp = (const float*)d_in[3];
    float* ws  = (float*)d_ws;
    float* out = (float*)d_out;

    void* args[] = { (void*)&sq, (void*)&sp, (void*)&tq, (void*)&tp,
                     (void*)&ws, (void*)&out };
    hipLaunchCooperativeKernel(fused_kernel, dim3(896), dim3(256),
                               args, 0u, stream);
}

// Round 6
// 82.025 us; speedup vs baseline: 3.3566x; 1.3203x over previous
//
#include <hip/hip_runtime.h>
#include <math.h>

#define N2   256
#define DIM  768
#define EPSF 1e-8f
#define MAGIC 0x5A17F00Du

// ws layout (float offsets). Every word is written before read on every call
// (flags rely on the per-call 0xAA poison != MAGIC). Total ~535 KB.
// NOTE (measured R6): same-address device atomicAdd ~10us/1000 tail -> use
// per-block flags (distinct addresses), not a shared counter.
// NOTE (measured R4/R14): __threadfence()/grid.sync() = per-block buffer_wbl2
// + buffer_inv; 896 blocks x 2 syncs = 204us kernel. Device-scope coherence
// must be flag+sc1 handshakes, never wholesale L2 flushes.
// NOTE (measured R15): ALL-blocks x 128-lane sc1 spin on 8 flag lines =
// LLC same-line storm; consumer polling starved producer loads -> 45.7us
// kernel (VALUBusy 12.6%). Barrier release must be single-aggregator +
// 1-lane-per-block poll on spread lines.
// NOTE (R13 decomposition): dur_us = harness 256MiB poison fill (~40us) +
// ~8us/node gaps + kernel work. 3-kernel version = ~10us work. Fixed floor
// ~56-60us regardless of kernel structure.
// NOTE (R16): regular launch (not cooperative; coop added ~6-12us node
// overhead). Safe: __launch_bounds__(256,4) -> 1024 co-resident capacity >=
// 896 grid, ascending dispatch -> producers resident before consumers spin;
// every block passes barrier 1 before any block exits.
#define OFF_G     0u          // [2][65536] reduced Gram (s, t)   512 KB
#define OFF_DIAG  131072u     // [2][256]   diagonals
#define OFF_TSUM  131584u     // [2][64]    per-tile sums
#define OFF_SLOT  131712u     // [896] per-block result slots
#define OFF_FLAG1 132608u     // [128] gemm-done flags
#define OFF_FLAG2 132736u     // [896] phaseB-done flags
#define OFF_READY 133632u     // [8 x 16-float-stride] barrier-1 release copies
#define SL_ANG  0     // [512]
#define SL_DIST 512   // [256]
#define SL_CON  768   // [128]

typedef __attribute__((ext_vector_type(8))) short short8;   // 8 bf16 = 4 VGPRs
typedef __attribute__((ext_vector_type(4))) float f32x4;

__device__ inline float wave_reduce_sum(float v) {
    #pragma unroll
    for (int o = 32; o > 0; o >>= 1) v += __shfl_down(v, o, 64);
    return v;
}
__device__ inline float wave_reduce_max(float v) {
    #pragma unroll
    for (int o = 32; o > 0; o >>= 1) v = fmaxf(v, __shfl_down(v, o, 64));
    return v;
}
__device__ inline float block_reduce_sum(float v, volatile float* red) {
    float w = wave_reduce_sum(v);
    __syncthreads();
    if ((threadIdx.x & 63) == 0) red[threadIdx.x >> 6] = w;
    __syncthreads();
    return red[0] + red[1] + red[2] + red[3];
}
__device__ inline const float* rowptr(const float* q, const float* p, int r) {
    return (r < 128) ? (r * DIM + q) : ((r - 128) * DIM + p);
}
__device__ inline unsigned f2bf(float x) {      // fp32 -> bf16 (RNE)
    union { float f; unsigned u; } v; v.f = x;
    return (v.u + 0x7fffu + ((v.u >> 16) & 1u)) >> 16;
}
// agent-scope (sc1) accessors: write-through / L2-bypass, NO cache flushes.
__device__ inline void st_agent_f(float* p, float v) {
    __hip_atomic_store(p, v, __ATOMIC_RELAXED, __HIP_MEMORY_SCOPE_AGENT);
}
__device__ inline void st_agent_u(unsigned* p, unsigned v) {
    __hip_atomic_store(p, v, __ATOMIC_RELAXED, __HIP_MEMORY_SCOPE_AGENT);
}
__device__ inline unsigned ld_agent_u(const unsigned* p) {
    return __hip_atomic_load(p, __ATOMIC_RELAXED, __HIP_MEMORY_SCOPE_AGENT);
}

// ---------------------------------------------------------------------------
// Fused kernel, regular launch. 896 blocks x 256 threads.
// Phase A (blocks 0..127): full-K Gram GEMM -> sc1 stores -> flag1[b].
// Barrier 1: block 0 aggregates flag1[0..127] -> READY[8 lines];
//            every block polls ONE READY word with ONE lane (+s_sleep).
// Phase B: blocks 0..511 angle, 512..767 dist rows, 768..895 contrastive.
//          Slot sc1 store -> vmcnt(0) -> flag2[b].
// Phase C: block 0 spins flag2[0..895], finalizes into out.
// LDS union 36.9 KB -> 4 blocks/CU -> 1024 co-resident capacity >= 896.
// ---------------------------------------------------------------------------
__global__ __launch_bounds__(256, 4) void fused_kernel(
        const float* __restrict__ sq, const float* __restrict__ sp,
        const float* __restrict__ tq, const float* __restrict__ tp,
        float* __restrict__ ws, float* __restrict__ out) {
    __shared__ union {
        struct { unsigned short A[32][104]; unsigned short B[32][104]; } g;
        struct { float GJ[16][68], TJ[16][68], IJ[16][68], ITJ[16][68];
                 float GI[32][68], TI[32][68];
                 float dgS[256], dgT[256]; } a;
    } sm;
    __shared__ float red1[4], red2[4], redS[1];
    const int b = blockIdx.x, t = threadIdx.x;

    // ======================= Phase A: Gram GEMM =======================
    if (b < 128) {
        const int mat = b & 1, tile = b >> 1;
        const int m0 = (tile >> 3) * 32, n0 = (tile & 7) * 32;
        const float* q = mat ? tq : sq;
        const float* p = mat ? tp : sp;

        // staging: 8 threads/row, each owns 12 floats (3 float4) per array
        const int srow = t >> 3, skq = (t & 7) * 12;
        const float* arow = rowptr(q, p, m0 + srow) + skq;
        const float* brow = rowptr(q, p, n0 + srow) + skq;

        float4 pa[3], pb[3];
        #pragma unroll
        for (int m = 0; m < 3; ++m) {
            pa[m] = *(const float4*)&arow[4 * m];
            pb[m] = *(const float4*)&brow[4 * m];
        }

        const int wave = t >> 6, lane = t & 63;
        const int wm = (wave >> 1) * 16, wn = (wave & 1) * 16;
        const int fr = lane & 15;          // fragment row/col
        const int fk = (lane >> 4) * 8;    // fragment k base
        f32x4 acc = {0.f, 0.f, 0.f, 0.f};

        for (int c = 0; c < 8; ++c) {
            // convert prefetched regs -> LDS
            #pragma unroll
            for (int m = 0; m < 3; ++m) {
                uint2 ap, bp;
                ap.x = f2bf(pa[m].x) | (f2bf(pa[m].y) << 16);
                ap.y = f2bf(pa[m].z) | (f2bf(pa[m].w) << 16);
                bp.x = f2bf(pb[m].x) | (f2bf(pb[m].y) << 16);
                bp.y = f2bf(pb[m].z) | (f2bf(pb[m].w) << 16);
                *(uint2*)&sm.g.A[srow][skq + 4 * m] = ap;
                *(uint2*)&sm.g.B[srow][skq + 4 * m] = bp;
            }
            __syncthreads();
            if (c < 7) {      // prefetch next chunk
                const int kb = (c + 1) * 96;
                #pragma unroll
                for (int m = 0; m < 3; ++m) {
                    pa[m] = *(const float4*)&arow[kb + 4 * m];
                    pb[m] = *(const float4*)&brow[kb + 4 * m];
                }
            }
            #pragma unroll
            for (int kc = 0; kc < 96; kc += 32) {
                const short8 a0 = *(const short8*)&sm.g.A[wm + fr][kc + fk];
                const short8 b0 = *(const short8*)&sm.g.B[wn + fr][kc + fk];
                acc = __builtin_amdgcn_mfma_f32_16x16x32_bf16(a0, b0, acc, 0, 0, 0);
            }
            __syncthreads();
        }

        // epilogue: C/D layout row=(lane>>4)*4+reg, col=lane&15
        // sc1 stores -> data lands at LLC, visible to all XCDs post-flag.
        float* G = ws + OFF_G + (unsigned)mat * 65536u;
        const int crow0 = (lane >> 4) * 4;
        const int ccol = lane & 15;
        float ts = 0.f;
        #pragma unroll
        for (int reg = 0; reg < 4; ++reg) {
            const int row = m0 + wm + crow0 + reg;
            const int col = n0 + wn + ccol;
            st_agent_f(&G[row * 256 + col], acc[reg]);
            ts += acc[reg];
        }
        if (m0 == n0 && wm == wn && (lane >> 4) == (ccol >> 2)) {
            // diagonal lanes: reg = ccol&3 hits row==col within diag quadrant
            st_agent_f(&ws[OFF_DIAG + (unsigned)(mat * 256 + m0 + wm + ccol)],
                       acc[ccol & 3]);
        }
        const float tsum = block_reduce_sum(ts, red1);   // drains all waves' stores
        if (t == 0) {
            st_agent_f(&ws[OFF_TSUM + (unsigned)(mat * 64 + tile)], tsum);
            asm volatile("s_waitcnt vmcnt(0)" ::: "memory");
            st_agent_u((unsigned*)(ws + OFF_FLAG1) + b, MAGIC);
        }
    }

    // ---- barrier 1: single-aggregator release (no polling storm).
    if (b == 0) {
        if (t < 128) {      // one block, 128 lanes: cheap poll of 128 flags
            while (ld_agent_u((const unsigned*)(ws + OFF_FLAG1) + t) != MAGIC)
                __builtin_amdgcn_s_sleep(4);
        }
        __syncthreads();
        if (t < 8)          // fan out to 8 copies on 8 distinct cache lines
            st_agent_u((unsigned*)(ws + OFF_READY) + t * 16, MAGIC);
    }
    if (t == 0) {           // ONE lane per block polls ONE spread READY copy
        while (ld_agent_u((const unsigned*)(ws + OFF_READY) + (b & 7) * 16) != MAGIC)
            __builtin_amdgcn_s_sleep(8);
    }
    __builtin_amdgcn_sched_barrier(0);
    asm volatile("" ::: "memory");
    __syncthreads();   // also retires phase-A LDS (union) before reuse

    // ======================= Phase B =======================
    const float* Pg = ws + OFF_G;      // [2][65536]  (normal cached loads: no
    const float* Dg = ws + OFF_DIAG;   //  XCD L2 holds stale lines: L2 inv'd at
                                       //  kernel start, first touch post-barrier)
    if (b < 512) {
        // ---------------- angle ----------------
        const int k0 = (b & 3) * 64;
        const int j0 = ((b >> 2) & 15) * 16;
        const int i0 = (b >> 6) * 32;
        const int jj = t & 15, ii = t >> 4;
        const int i1 = i0 + ii, i2 = i1 + 16, j = j0 + jj;

        // diag (thread t owns index t)
        sm.a.dgS[t] = Dg[t];
        sm.a.dgT[t] = Dg[256 + t];

        // J-side G rows -> registers (1 float4 slot/thread)
        const int r = t >> 4, c4 = (t & 15) * 4;
        const unsigned baseJ = (unsigned)((j0 + r) * 256 + k0 + c4);
        const float4 gjs = *(const float4*)&Pg[baseJ];
        const float4 gjt = *(const float4*)&Pg[65536u + baseJ];

        // I-side G rows -> LDS (2 float4 slots/thread)
        #pragma unroll
        for (int s2 = 0; s2 < 2; ++s2) {
            const int slot = t + 256 * s2;
            const int ri = slot >> 4, ci = (slot & 15) * 4;
            const unsigned base = (unsigned)((i0 + ri) * 256 + k0 + ci);
            *(float4*)&sm.a.GI[ri][ci] = *(const float4*)&Pg[base];
            *(float4*)&sm.a.TI[ri][ci] = *(const float4*)&Pg[65536u + base];
        }
        // per-thread G[i1,j], G[i2,j] (both mats)
        const float g1s = Pg[(unsigned)(i1 * 256 + j)];
        const float g1t = Pg[65536u + (unsigned)(i1 * 256 + j)];
        const float g2s = Pg[(unsigned)(i2 * 256 + j)];
        const float g2t = Pg[65536u + (unsigned)(i2 * 256 + j)];
        __syncthreads();   // dgS/dgT ready

        // write J arrays + on-the-fly INV
        {
            const float djs = sm.a.dgS[j0 + r], djt = sm.a.dgT[j0 + r];
            float4 ivs, ivt;
            const float* dS = &sm.a.dgS[k0 + c4];
            const float* dT = &sm.a.dgT[k0 + c4];
            ivs.x = 1.f / (sqrtf(fmaxf(djs + dS[0] - 2.f * gjs.x, 0.f)) + EPSF);
            ivs.y = 1.f / (sqrtf(fmaxf(djs + dS[1] - 2.f * gjs.y, 0.f)) + EPSF);
            ivs.z = 1.f / (sqrtf(fmaxf(djs + dS[2] - 2.f * gjs.z, 0.f)) + EPSF);
            ivs.w = 1.f / (sqrtf(fmaxf(djs + dS[3] - 2.f * gjs.w, 0.f)) + EPSF);
            ivt.x = 1.f / (sqrtf(fmaxf(djt + dT[0] - 2.f * gjt.x, 0.f)) + EPSF);
            ivt.y = 1.f / (sqrtf(fmaxf(djt + dT[1] - 2.f * gjt.y, 0.f)) + EPSF);
            ivt.z = 1.f / (sqrtf(fmaxf(djt + dT[2] - 2.f * gjt.z, 0.f)) + EPSF);
            ivt.w = 1.f / (sqrtf(fmaxf(djt + dT[3] - 2.f * gjt.w, 0.f)) + EPSF);
            *(float4*)&sm.a.GJ[r][c4] = gjs;
            *(float4*)&sm.a.TJ[r][c4] = gjt;
            *(float4*)&sm.a.IJ[r][c4] = ivs;
            *(float4*)&sm.a.ITJ[r][c4] = ivt;
        }
        // per-thread constants
        const float Gjj = sm.a.dgS[j], Tjj = sm.a.dgT[j];
        const float wis1 = 1.f / (sqrtf(fmaxf(sm.a.dgS[i1] + Gjj - 2.f * g1s, 0.f)) + EPSF);
        const float wit1 = 1.f / (sqrtf(fmaxf(sm.a.dgT[i1] + Tjj - 2.f * g1t, 0.f)) + EPSF);
        const float wis2 = 1.f / (sqrtf(fmaxf(sm.a.dgS[i2] + Gjj - 2.f * g2s, 0.f)) + EPSF);
        const float wit2 = 1.f / (sqrtf(fmaxf(sm.a.dgT[i2] + Tjj - 2.f * g2t, 0.f)) + EPSF);
        const float as1 = (Gjj - g1s) * wis1;
        const float at1 = (Tjj - g1t) * wit1;
        const float as2 = (Gjj - g2s) * wis2;
        const float at2 = (Tjj - g2t) * wit2;
        __syncthreads();   // all arrays ready

        float sum1 = 0.f, sum2 = 0.f;
        for (int c = 0; c < 64; c += 4) {
            const float4 gJ  = *(const float4*)&sm.a.GJ[jj][c];
            const float4 iJ  = *(const float4*)&sm.a.IJ[jj][c];
            const float4 tJ  = *(const float4*)&sm.a.TJ[jj][c];
            const float4 itJ = *(const float4*)&sm.a.ITJ[jj][c];
            const float4 a1 = *(const float4*)&sm.a.GI[ii][c];
            const float4 b1 = *(const float4*)&sm.a.TI[ii][c];
            const float4 a2 = *(const float4*)&sm.a.GI[ii + 16][c];
            const float4 b2 = *(const float4*)&sm.a.TI[ii + 16][c];
            const float gJr[4]  = {gJ.x, gJ.y, gJ.z, gJ.w};
            const float iJr[4]  = {iJ.x, iJ.y, iJ.z, iJ.w};
            const float tJr[4]  = {tJ.x, tJ.y, tJ.z, tJ.w};
            const float itJr[4] = {itJ.x, itJ.y, itJ.z, itJ.w};
            const float a1r[4] = {a1.x, a1.y, a1.z, a1.w};
            const float b1r[4] = {b1.x, b1.y, b1.z, b1.w};
            const float a2r[4] = {a2.x, a2.y, a2.z, a2.w};
            const float b2r[4] = {b2.x, b2.y, b2.z, b2.w};
            #pragma unroll
            for (int e = 0; e < 4; ++e) {
                const float ps1 = fmaf(wis1, a1r[e] - gJr[e], as1) * iJr[e];
                const float pt1 = fmaf(wit1, b1r[e] - tJr[e], at1) * itJr[e];
                const float d1 = ps1 - pt1;
                const float ad1 = fabsf(d1);
                const float m1 = fminf(ad1, 1.f);
                sum1 = fmaf(m1, fmaf(-0.5f, m1, ad1), sum1);

                const float ps2 = fmaf(wis2, a2r[e] - gJr[e], as2) * iJr[e];
                const float pt2 = fmaf(wit2, b2r[e] - tJr[e], at2) * itJr[e];
                const float d2 = ps2 - pt2;
                const float ad2 = fabsf(d2);
                const float m2 = fminf(ad2, 1.f);
                sum2 = fmaf(m2, fmaf(-0.5f, m2, ad2), sum2);
            }
        }
        const float v = block_reduce_sum(sum1 + sum2, red1);
        if (t == 0) {
            st_agent_f(ws + OFF_SLOT + SL_ANG + b, v);
            asm volatile("s_waitcnt vmcnt(0)" ::: "memory");
            st_agent_u((unsigned*)(ws + OFF_FLAG2) + b, MAGIC);
        }
    } else if (b < 768) {
        // ---------------- distance row ----------------
        const int i = b - 512, j = t;
        const float gs  = Pg[(unsigned)(i * 256 + j)];
        const float gt  = Pg[65536u + (unsigned)(i * 256 + j)];
        const float djs = Dg[j], djt = Dg[256 + j];
        const float dis = Dg[i], dit = Dg[256 + i];
        const float ds = fmaxf(dis + djs - 2.f * gs, 0.f);
        const float dt = fmaxf(dit + djt - 2.f * gt, 0.f);

        // analytic masked pair-sums: sum_{i<j} d = N*tr - sum_all(G)
        const float tr_s = block_reduce_sum(djs, red1);
        const float tr_t = block_reduce_sum(djt, red1);
        const float tv = (t < 128) ? ws[OFF_TSUM + t] : 0.f;  // [2][64] linear
        const float sum_gs = block_reduce_sum((t < 64) ? tv : 0.f, red1);
        const float sum_gt = block_reduce_sum((t >= 64) ? tv : 0.f, red1);
        const float rs = 1.f / ((256.f * tr_s - sum_gs) / 32640.f + EPSF);
        const float rt = 1.f / ((256.f * tr_t - sum_gt) / 32640.f + EPSF);

        const float dd = ds * rs - dt * rt;
        const float a = fabsf(dd);
        const float m = fminf(a, 1.f);
        const float hv = block_reduce_sum((j > i) ? m * fmaf(-0.5f, m, a) : 0.f, red1);
        if (t == 0) {
            st_agent_f(ws + OFF_SLOT + SL_DIST + i, hv);
            asm volatile("s_waitcnt vmcnt(0)" ::: "memory");
            st_agent_u((unsigned*)(ws + OFF_FLAG2) + b, MAGIC);
        }
    } else {
        // ---------------- contrastive row ----------------
        const int rrow = b - 768, j = t;
        const float gs = (j >= 128) ? Pg[(unsigned)(rrow * 256 + j)] : 0.f;
        const float s = (j >= 128) ? 20.f * gs : -INFINITY;
        if (j == 128 + rrow) redS[0] = s;     // diag score
        float mx0 = wave_reduce_max(s);
        __syncthreads();
        if ((t & 63) == 0) red2[t >> 6] = mx0;
        __syncthreads();
        const float mx = fmaxf(fmaxf(red2[0], red2[1]), fmaxf(red2[2], red2[3]));
        const float e = block_reduce_sum((j >= 128) ? expf(s - mx) : 0.f, red1);
        if (t == 0) {
            st_agent_f(ws + OFF_SLOT + SL_CON + rrow, mx + logf(e) - redS[0]);
            asm volatile("s_waitcnt vmcnt(0)" ::: "memory");
            st_agent_u((unsigned*)(ws + OFF_FLAG2) + b, MAGIC);
        }
    }

    // ======================= Phase C: finalize (block 0 only) ===============
    if (b == 0) {
        for (int k = t; k < 896; k += 256) {   // one block polling: no storm
            while (ld_agent_u((const unsigned*)(ws + OFF_FLAG2) + k) != MAGIC)
                __builtin_amdgcn_s_sleep(4);
        }
        __builtin_amdgcn_sched_barrier(0);
        asm volatile("" ::: "memory");
        __syncthreads();

        const float* S = ws + OFF_SLOT;
        const float a_ = block_reduce_sum(S[SL_ANG + t] + S[SL_ANG + 256 + t], red1);
        const float d_ = block_reduce_sum(S[SL_DIST + t], red1);
        const float c_ = block_reduce_sum((t < 128) ? S[SL_CON + t] : 0.f, red1);
        if (t == 0) {
            const float contrastive = c_ / 128.f;
            const float dist = d_ / 32640.f;
            const float ang = a_ / 16581120.f;   // 256*255*254
            const float kd = 0.5f * (dist + ang);
            out[0] = contrastive + kd;
            out[1] = contrastive;
            out[2] = kd;
        }
    }
}

extern "C" void kernel_launch(void* const* d_in, const int* in_sizes, int n_in,
                              void* d_out, int out_size, void* d_ws, size_t ws_size,
                              hipStream_t stream) {
    (void)in_sizes; (void)n_in; (void)out_size; (void)ws_size;
    const float* sq = (const float*)d_in[0];
    const float* sp = (const float*)d_in[1];
    const float* tq = (const float*)d_in[2];
    const float* tp = (const float*)d_in[3];
    float* ws  = (float*)d_ws;
    float* out = (float*)d_out;

    fused_kernel<<<896, 256, 0, stream>>>(sq, sp, tq, tp, ws, out);
}

// Round 7
// 76.783 us; speedup vs baseline: 3.5857x; 1.0683x over previous
//
#include <hip/hip_runtime.h>
#include <math.h>

#define N2   256
#define DIM  768
#define EPSF 1e-8f
#define MAGIC 0x5A17F00Du

// ws layout (float offsets). Every word is written before read on every call
// (flags rely on the per-call 0xAA poison != MAGIC; fill measured present
// every iteration at ~40us). Total ~535 KB.
// NOTE (measured R4/R14): __threadfence()/grid.sync() = per-block L2
// wb+inv -> 204us. Never wholesale-flush; use kernel boundaries or sc1 flags.
// NOTE (measured R15): all-blocks sc1 spin on few lines = LLC storm (45.7us
// kernel). NOTE (measured R16): even a 2-level in-kernel barrier gating 896
// consumers on 128 producers (+768 parked blocks) loses to a kernel boundary:
// R16 fused 2-node = 82.0 vs R13 3-node = 77.7. Producer->all-consumer sync
// belongs on a kernel boundary; only the cheap mega->finalize sync (896
// co-resident producers, 1 tiny consumer block) is worth fusing (this round).
// NOTE (R9): GEMM uses bf16 MFMA (fp32->bf16 RNE at staging); symmetric
// dot-product uses make tile-transpose conventions cancel.
// NOTE (R10, measured R13): full-K Gram, no split-K partials.
// NOTE (R13 decomposition): dur = 256MiB poison fill (~40us) + ~7us/node +
// ~10us total kernel work. Node-count is the main remaining lever.
#define OFF_G     0u          // [2][65536] reduced Gram (s, t)   512 KB
#define OFF_DIAG  131072u     // [2][256]   diagonals
#define OFF_TSUM  131584u     // [2][64]    per-tile sums
#define OFF_SLOT  131712u     // [896] per-block result slots (sc1-only lines)
#define OFF_FLAG2 132608u     // [896] phaseB-done flags       (sc1-only lines)
#define SL_ANG  0     // [512]
#define SL_DIST 512   // [256]
#define SL_CON  768   // [128]

typedef __attribute__((ext_vector_type(8))) short short8;   // 8 bf16 = 4 VGPRs
typedef __attribute__((ext_vector_type(4))) float f32x4;

__device__ inline float wave_reduce_sum(float v) {
    #pragma unroll
    for (int o = 32; o > 0; o >>= 1) v += __shfl_down(v, o, 64);
    return v;
}
__device__ inline float wave_reduce_max(float v) {
    #pragma unroll
    for (int o = 32; o > 0; o >>= 1) v = fmaxf(v, __shfl_down(v, o, 64));
    return v;
}
__device__ inline float block_reduce_sum(float v, volatile float* red) {
    float w = wave_reduce_sum(v);
    __syncthreads();
    if ((threadIdx.x & 63) == 0) red[threadIdx.x >> 6] = w;
    __syncthreads();
    return red[0] + red[1] + red[2] + red[3];
}
__device__ inline const float* rowptr(const float* q, const float* p, int r) {
    return (r < 128) ? (r * DIM + q) : ((r - 128) * DIM + p);
}
__device__ inline unsigned f2bf(float x) {      // fp32 -> bf16 (RNE)
    union { float f; unsigned u; } v; v.f = x;
    return (v.u + 0x7fffu + ((v.u >> 16) & 1u)) >> 16;
}
// agent-scope (sc1) accessors: LLC-direct, no cache flushes.
__device__ inline void st_agent_f(float* p, float v) {
    __hip_atomic_store(p, v, __ATOMIC_RELAXED, __HIP_MEMORY_SCOPE_AGENT);
}
__device__ inline float ld_agent_f(const float* p) {
    return __hip_atomic_load(p, __ATOMIC_RELAXED, __HIP_MEMORY_SCOPE_AGENT);
}
__device__ inline void st_agent_u(unsigned* p, unsigned v) {
    __hip_atomic_store(p, v, __ATOMIC_RELAXED, __HIP_MEMORY_SCOPE_AGENT);
}
__device__ inline unsigned ld_agent_u(const unsigned* p) {
    return __hip_atomic_load(p, __ATOMIC_RELAXED, __HIP_MEMORY_SCOPE_AGENT);
}

// ---------------------------------------------------------------------------
// K1: full-K Gram GEMM via bf16 MFMA. 128 blocks x 256 threads. Normal
// stores; the following kernel boundary is the (free) coherence point.
// ---------------------------------------------------------------------------
__global__ __launch_bounds__(256) void gemm_kernel(
        const float* __restrict__ sq, const float* __restrict__ sp,
        const float* __restrict__ tq, const float* __restrict__ tp,
        float* __restrict__ ws) {
    const int b = blockIdx.x, t = threadIdx.x;
    const int mat = b & 1, tile = b >> 1;
    const int m0 = (tile >> 3) * 32, n0 = (tile & 7) * 32;
    const float* q = mat ? tq : sq;
    const float* p = mat ? tp : sp;

    __shared__ unsigned short Asb[32][104];   // bf16 [row][k], pad->208B rows
    __shared__ unsigned short Bsb[32][104];
    __shared__ float redg[4];

    // staging: 8 threads/row, each owns 12 floats (3 float4) per array
    const int srow = t >> 3, skq = (t & 7) * 12;
    const float* arow = rowptr(q, p, m0 + srow) + skq;
    const float* brow = rowptr(q, p, n0 + srow) + skq;

    float4 pa[3], pb[3];
    #pragma unroll
    for (int m = 0; m < 3; ++m) {
        pa[m] = *(const float4*)&arow[4 * m];
        pb[m] = *(const float4*)&brow[4 * m];
    }

    const int wave = t >> 6, lane = t & 63;
    const int wm = (wave >> 1) * 16, wn = (wave & 1) * 16;
    const int fr = lane & 15;          // fragment row/col
    const int fk = (lane >> 4) * 8;    // fragment k base
    f32x4 acc = {0.f, 0.f, 0.f, 0.f};

    for (int c = 0; c < 8; ++c) {
        // convert prefetched regs -> LDS
        #pragma unroll
        for (int m = 0; m < 3; ++m) {
            uint2 ap, bp;
            ap.x = f2bf(pa[m].x) | (f2bf(pa[m].y) << 16);
            ap.y = f2bf(pa[m].z) | (f2bf(pa[m].w) << 16);
            bp.x = f2bf(pb[m].x) | (f2bf(pb[m].y) << 16);
            bp.y = f2bf(pb[m].z) | (f2bf(pb[m].w) << 16);
            *(uint2*)&Asb[srow][skq + 4 * m] = ap;
            *(uint2*)&Bsb[srow][skq + 4 * m] = bp;
        }
        __syncthreads();
        if (c < 7) {      // prefetch next chunk
            const int kb = (c + 1) * 96;
            #pragma unroll
            for (int m = 0; m < 3; ++m) {
                pa[m] = *(const float4*)&arow[kb + 4 * m];
                pb[m] = *(const float4*)&brow[kb + 4 * m];
            }
        }
        #pragma unroll
        for (int kc = 0; kc < 96; kc += 32) {
            const short8 a0 = *(const short8*)&Asb[wm + fr][kc + fk];
            const short8 b0 = *(const short8*)&Bsb[wn + fr][kc + fk];
            acc = __builtin_amdgcn_mfma_f32_16x16x32_bf16(a0, b0, acc, 0, 0, 0);
        }
        __syncthreads();
    }

    // epilogue: C/D layout row=(lane>>4)*4+reg, col=lane&15
    float* G = ws + OFF_G + (unsigned)mat * 65536u;
    const int crow0 = (lane >> 4) * 4;
    const int ccol = lane & 15;
    float ts = 0.f;
    #pragma unroll
    for (int reg = 0; reg < 4; ++reg) {
        const int row = m0 + wm + crow0 + reg;
        const int col = n0 + wn + ccol;
        G[row * 256 + col] = acc[reg];
        ts += acc[reg];
    }
    if (m0 == n0 && wm == wn && (lane >> 4) == (ccol >> 2)) {
        // diagonal lanes: reg = ccol&3 hits row==col within diagonal quadrant
        ws[OFF_DIAG + (unsigned)(mat * 256 + m0 + wm + ccol)] = acc[ccol & 3];
    }
    const float tsum = block_reduce_sum(ts, redg);
    if (t == 0) ws[OFF_TSUM + (unsigned)(mat * 64 + tile)] = tsum;
}

// ---------------------------------------------------------------------------
// K2: mega kernel + inline finalize. 896 blocks x 256 threads, all
// co-resident (LDS 36.9KB + bounds(256,4) -> 4/CU -> capacity 1024 >= 896).
// blocks 0..511 angle, 512..767 dist, 768..895 contrastive. Each block's t0:
// slot sc1 store -> vmcnt(0) -> flag sc1 store. Block 0 then polls the 896
// flags and finalizes into out (sc1 slot reads; slot/flag lines are
// sc1-only so no XCD L2 ever caches them).
// ---------------------------------------------------------------------------
__global__ __launch_bounds__(256, 4) void mega_kernel(float* __restrict__ ws,
                                                      float* __restrict__ out) {
    const float* Pg = ws + OFF_G;      // [2][65536]
    const float* Dg = ws + OFF_DIAG;   // [2][256]
    __shared__ float sGJ[16][68], sTJ[16][68], sIJ[16][68], sITJ[16][68];
    __shared__ float sGI[32][68], sTI[32][68];
    __shared__ float dgS[256], dgT[256];
    __shared__ float red1[4], red2[4], redS[1];
    const int b = blockIdx.x, t = threadIdx.x;

    if (b < 512) {
        // ---------------- angle ----------------
        const int k0 = (b & 3) * 64;
        const int j0 = ((b >> 2) & 15) * 16;
        const int i0 = (b >> 6) * 32;
        const int jj = t & 15, ii = t >> 4;
        const int i1 = i0 + ii, i2 = i1 + 16, j = j0 + jj;

        // diag (thread t owns index t)
        dgS[t] = Dg[t];
        dgT[t] = Dg[256 + t];

        // J-side G rows -> registers (1 float4 slot/thread)
        const int r = t >> 4, c4 = (t & 15) * 4;
        const unsigned baseJ = (unsigned)((j0 + r) * 256 + k0 + c4);
        const float4 gjs = *(const float4*)&Pg[baseJ];
        const float4 gjt = *(const float4*)&Pg[65536u + baseJ];

        // I-side G rows -> LDS (2 float4 slots/thread)
        #pragma unroll
        for (int s2 = 0; s2 < 2; ++s2) {
            const int slot = t + 256 * s2;
            const int ri = slot >> 4, ci = (slot & 15) * 4;
            const unsigned base = (unsigned)((i0 + ri) * 256 + k0 + ci);
            *(float4*)&sGI[ri][ci] = *(const float4*)&Pg[base];
            *(float4*)&sTI[ri][ci] = *(const float4*)&Pg[65536u + base];
        }
        // per-thread G[i1,j], G[i2,j] (both mats)
        const float g1s = Pg[(unsigned)(i1 * 256 + j)];
        const float g1t = Pg[65536u + (unsigned)(i1 * 256 + j)];
        const float g2s = Pg[(unsigned)(i2 * 256 + j)];
        const float g2t = Pg[65536u + (unsigned)(i2 * 256 + j)];
        __syncthreads();   // dgS/dgT ready

        // write J arrays + on-the-fly INV
        {
            const float djs = dgS[j0 + r], djt = dgT[j0 + r];
            float4 ivs, ivt;
            const float* dS = &dgS[k0 + c4];
            const float* dT = &dgT[k0 + c4];
            ivs.x = 1.f / (sqrtf(fmaxf(djs + dS[0] - 2.f * gjs.x, 0.f)) + EPSF);
            ivs.y = 1.f / (sqrtf(fmaxf(djs + dS[1] - 2.f * gjs.y, 0.f)) + EPSF);
            ivs.z = 1.f / (sqrtf(fmaxf(djs + dS[2] - 2.f * gjs.z, 0.f)) + EPSF);
            ivs.w = 1.f / (sqrtf(fmaxf(djs + dS[3] - 2.f * gjs.w, 0.f)) + EPSF);
            ivt.x = 1.f / (sqrtf(fmaxf(djt + dT[0] - 2.f * gjt.x, 0.f)) + EPSF);
            ivt.y = 1.f / (sqrtf(fmaxf(djt + dT[1] - 2.f * gjt.y, 0.f)) + EPSF);
            ivt.z = 1.f / (sqrtf(fmaxf(djt + dT[2] - 2.f * gjt.z, 0.f)) + EPSF);
            ivt.w = 1.f / (sqrtf(fmaxf(djt + dT[3] - 2.f * gjt.w, 0.f)) + EPSF);
            *(float4*)&sGJ[r][c4] = gjs;
            *(float4*)&sTJ[r][c4] = gjt;
            *(float4*)&sIJ[r][c4] = ivs;
            *(float4*)&sITJ[r][c4] = ivt;
        }
        // per-thread constants
        const float Gjj = dgS[j], Tjj = dgT[j];
        const float wis1 = 1.f / (sqrtf(fmaxf(dgS[i1] + Gjj - 2.f * g1s, 0.f)) + EPSF);
        const float wit1 = 1.f / (sqrtf(fmaxf(dgT[i1] + Tjj - 2.f * g1t, 0.f)) + EPSF);
        const float wis2 = 1.f / (sqrtf(fmaxf(dgS[i2] + Gjj - 2.f * g2s, 0.f)) + EPSF);
        const float wit2 = 1.f / (sqrtf(fmaxf(dgT[i2] + Tjj - 2.f * g2t, 0.f)) + EPSF);
        const float as1 = (Gjj - g1s) * wis1;
        const float at1 = (Tjj - g1t) * wit1;
        const float as2 = (Gjj - g2s) * wis2;
        const float at2 = (Tjj - g2t) * wit2;
        __syncthreads();   // all arrays ready

        float sum1 = 0.f, sum2 = 0.f;
        for (int c = 0; c < 64; c += 4) {
            const float4 gJ  = *(const float4*)&sGJ[jj][c];
            const float4 iJ  = *(const float4*)&sIJ[jj][c];
            const float4 tJ  = *(const float4*)&sTJ[jj][c];
            const float4 itJ = *(const float4*)&sITJ[jj][c];
            const float4 a1 = *(const float4*)&sGI[ii][c];
            const float4 b1 = *(const float4*)&sTI[ii][c];
            const float4 a2 = *(const float4*)&sGI[ii + 16][c];
            const float4 b2 = *(const float4*)&sTI[ii + 16][c];
            const float gJr[4]  = {gJ.x, gJ.y, gJ.z, gJ.w};
            const float iJr[4]  = {iJ.x, iJ.y, iJ.z, iJ.w};
            const float tJr[4]  = {tJ.x, tJ.y, tJ.z, tJ.w};
            const float itJr[4] = {itJ.x, itJ.y, itJ.z, itJ.w};
            const float a1r[4] = {a1.x, a1.y, a1.z, a1.w};
            const float b1r[4] = {b1.x, b1.y, b1.z, b1.w};
            const float a2r[4] = {a2.x, a2.y, a2.z, a2.w};
            const float b2r[4] = {b2.x, b2.y, b2.z, b2.w};
            #pragma unroll
            for (int e = 0; e < 4; ++e) {
                const float ps1 = fmaf(wis1, a1r[e] - gJr[e], as1) * iJr[e];
                const float pt1 = fmaf(wit1, b1r[e] - tJr[e], at1) * itJr[e];
                const float d1 = ps1 - pt1;
                const float ad1 = fabsf(d1);
                const float m1 = fminf(ad1, 1.f);
                sum1 = fmaf(m1, fmaf(-0.5f, m1, ad1), sum1);

                const float ps2 = fmaf(wis2, a2r[e] - gJr[e], as2) * iJr[e];
                const float pt2 = fmaf(wit2, b2r[e] - tJr[e], at2) * itJr[e];
                const float d2 = ps2 - pt2;
                const float ad2 = fabsf(d2);
                const float m2 = fminf(ad2, 1.f);
                sum2 = fmaf(m2, fmaf(-0.5f, m2, ad2), sum2);
            }
        }
        const float v = block_reduce_sum(sum1 + sum2, red1);
        if (t == 0) {
            st_agent_f(ws + OFF_SLOT + SL_ANG + b, v);
            asm volatile("s_waitcnt vmcnt(0)" ::: "memory");
            st_agent_u((unsigned*)(ws + OFF_FLAG2) + b, MAGIC);
        }
    } else if (b < 768) {
        // ---------------- distance row ----------------
        const int i = b - 512, j = t;
        const float gs  = Pg[(unsigned)(i * 256 + j)];
        const float gt  = Pg[65536u + (unsigned)(i * 256 + j)];
        const float djs = Dg[j], djt = Dg[256 + j];
        const float dis = Dg[i], dit = Dg[256 + i];
        const float ds = fmaxf(dis + djs - 2.f * gs, 0.f);
        const float dt = fmaxf(dit + djt - 2.f * gt, 0.f);

        // analytic masked pair-sums: sum_{i<j} d = N*tr - sum_all(G)
        const float tr_s = block_reduce_sum(djs, red1);
        const float tr_t = block_reduce_sum(djt, red1);
        const float tv = (t < 128) ? ws[OFF_TSUM + t] : 0.f;  // [2][64] linear
        const float sum_gs = block_reduce_sum((t < 64) ? tv : 0.f, red1);
        const float sum_gt = block_reduce_sum((t >= 64) ? tv : 0.f, red1);
        const float rs = 1.f / ((256.f * tr_s - sum_gs) / 32640.f + EPSF);
        const float rt = 1.f / ((256.f * tr_t - sum_gt) / 32640.f + EPSF);

        const float dd = ds * rs - dt * rt;
        const float a = fabsf(dd);
        const float m = fminf(a, 1.f);
        const float hv = block_reduce_sum((j > i) ? m * fmaf(-0.5f, m, a) : 0.f, red1);
        if (t == 0) {
            st_agent_f(ws + OFF_SLOT + SL_DIST + i, hv);
            asm volatile("s_waitcnt vmcnt(0)" ::: "memory");
            st_agent_u((unsigned*)(ws + OFF_FLAG2) + b, MAGIC);
        }
    } else {
        // ---------------- contrastive row ----------------
        const int rrow = b - 768, j = t;
        const float gs = (j >= 128) ? Pg[(unsigned)(rrow * 256 + j)] : 0.f;
        const float s = (j >= 128) ? 20.f * gs : -INFINITY;
        if (j == 128 + rrow) redS[0] = s;     // diag score
        float mx0 = wave_reduce_max(s);
        __syncthreads();
        if ((t & 63) == 0) red2[t >> 6] = mx0;
        __syncthreads();
        const float mx = fmaxf(fmaxf(red2[0], red2[1]), fmaxf(red2[2], red2[3]));
        const float e = block_reduce_sum((j >= 128) ? expf(s - mx) : 0.f, red1);
        if (t == 0) {
            st_agent_f(ws + OFF_SLOT + SL_CON + rrow, mx + logf(e) - redS[0]);
            asm volatile("s_waitcnt vmcnt(0)" ::: "memory");
            st_agent_u((unsigned*)(ws + OFF_FLAG2) + b, MAGIC);
        }
    }

    // ============== finalize (block 0 only; all 896 co-resident) ==========
    if (b == 0) {
        for (int k = t; k < 896; k += 256) {   // one block polls: no storm
            while (ld_agent_u((const unsigned*)(ws + OFF_FLAG2) + k) != MAGIC)
                __builtin_amdgcn_s_sleep(4);
        }
        asm volatile("s_waitcnt vmcnt(0)" ::: "memory");
        __builtin_amdgcn_sched_barrier(0);
        __syncthreads();

        float* S = ws + OFF_SLOT;
        const float a_ = block_reduce_sum(ld_agent_f(S + SL_ANG + t) +
                                          ld_agent_f(S + SL_ANG + 256 + t), red1);
        const float d_ = block_reduce_sum(ld_agent_f(S + SL_DIST + t), red1);
        const float c_ = block_reduce_sum((t < 128) ? ld_agent_f(S + SL_CON + t)
                                                    : 0.f, red1);
        if (t == 0) {
            const float contrastive = c_ / 128.f;
            const float dist = d_ / 32640.f;
            const float ang = a_ / 16581120.f;   // 256*255*254
            const float kd = 0.5f * (dist + ang);
            out[0] = contrastive + kd;
            out[1] = contrastive;
            out[2] = kd;
        }
    }
}

extern "C" void kernel_launch(void* const* d_in, const int* in_sizes, int n_in,
                              void* d_out, int out_size, void* d_ws, size_t ws_size,
                              hipStream_t stream) {
    (void)in_sizes; (void)n_in; (void)out_size; (void)ws_size;
    const float* sq = (const float*)d_in[0];
    const float* sp = (const float*)d_in[1];
    const float* tq = (const float*)d_in[2];
    const float* tp = (const float*)d_in[3];
    float* ws  = (float*)d_ws;
    float* out = (float*)d_out;

    gemm_kernel<<<128, 256, 0, stream>>>(sq, sp, tq, tp, ws);
    mega_kernel<<<896, 256, 0, stream>>>(ws, out);
}